// Round 1
// baseline (14.003 us; speedup 1.0000x reference)
//
#include <hip/hip_runtime.h>
#include <math.h>

// EstimatorQNN: 18-qubit circuit, depth 3, nearest-neighbor CZ.
// Exact light-cone reduction: <Z_i> depends only on qubits [i-2, i+2]
// (final CZ layer is diagonal -> commutes with Z_i; support grows by 1
// qubit per *inner* CZ layer only). Each (batch, qubit) output is an
// independent 5-qubit (32-amplitude) simulation held fully in registers.

#define NQ    18
#define NDEPTH 3
#define NBATCH 16
#define WQ     5      // window qubits
#define WA    32      // window amplitudes (2^WQ)

__global__ __launch_bounds__(64)
void qnn_lightcone_kernel(const float* __restrict__ x,
                          const float* __restrict__ params,
                          float* __restrict__ out) {
    const int tid = blockIdx.x * blockDim.x + threadIdx.x;
    if (tid >= NBATCH * NQ) return;
    const int b = tid / NQ;
    const int i = tid - b * NQ;

    // clamped 5-qubit window [s, s+4], target local position p
    int s = i - 2;
    if (s < 0) s = 0;
    if (s > NQ - WQ) s = NQ - WQ;
    const int p = i - s;

    // --- angles: cos/sin of theta/2 for RX (input x) and RY (params w) ---
    float cx[WQ], sx[WQ];
    float cw[NDEPTH][WQ], sw[NDEPTH][WQ];
#pragma unroll
    for (int q = 0; q < WQ; ++q) {
        float th = 0.5f * x[b * NQ + s + q];
        sincosf(th, &sx[q], &cx[q]);
    }
#pragma unroll
    for (int d = 0; d < NDEPTH; ++d) {
#pragma unroll
        for (int q = 0; q < WQ; ++q) {
            float th = 0.5f * params[NQ + d * NQ + s + q];
            sincosf(th, &sw[d][q], &cw[d][q]);
        }
    }

    // --- state: 32 complex amplitudes in registers, |00000> start ---
    float sr[WA], si[WA];
#pragma unroll
    for (int a = 0; a < WA; ++a) { sr[a] = 0.0f; si[a] = 0.0f; }
    sr[0] = 1.0f;

    // --- RX layer: v0' = c*v0 - i s*v1 ; v1' = -i s*v0 + c*v1 ---
#pragma unroll
    for (int q = 0; q < WQ; ++q) {
        const float c = cx[q], sn = sx[q];
#pragma unroll
        for (int a = 0; a < WA; ++a) {
            if (a & (1 << q)) continue;
            const int a1 = a | (1 << q);
            const float r0 = sr[a], i0 = si[a], r1 = sr[a1], i1 = si[a1];
            sr[a]  = c * r0 + sn * i1;
            si[a]  = c * i0 - sn * r1;
            sr[a1] = c * r1 + sn * i0;
            si[a1] = c * i1 - sn * r0;
        }
    }

    // --- depth layers: RY sweep then CZ chain (window-internal) ---
#pragma unroll
    for (int d = 0; d < NDEPTH; ++d) {
#pragma unroll
        for (int q = 0; q < WQ; ++q) {
            const float c = cw[d][q], sn = sw[d][q];
#pragma unroll
            for (int a = 0; a < WA; ++a) {
                if (a & (1 << q)) continue;
                const int a1 = a | (1 << q);
                const float r0 = sr[a], i0 = si[a], r1 = sr[a1], i1 = si[a1];
                sr[a]  = c * r0 - sn * r1;
                si[a]  = c * i0 - sn * i1;
                sr[a1] = sn * r0 + c * r1;
                si[a1] = sn * i0 + c * i1;
            }
        }
#pragma unroll
        for (int q = 0; q < WQ - 1; ++q) {
            const int m = (1 << q) | (1 << (q + 1));
#pragma unroll
            for (int a = 0; a < WA; ++a) {
                if ((a & m) == m) { sr[a] = -sr[a]; si[a] = -si[a]; }
            }
        }
    }

    // --- <Z_p> = sum |amp|^2 * (+1 if bit p == 0 else -1) ---
    float z = 0.0f;
#pragma unroll
    for (int a = 0; a < WA; ++a) {
        const float pr = sr[a] * sr[a] + si[a] * si[a];
        z += ((a >> p) & 1) ? -pr : pr;
    }
    out[b * NQ + i] = z;
}

extern "C" void kernel_launch(void* const* d_in, const int* in_sizes, int n_in,
                              void* d_out, int out_size, void* d_ws, size_t ws_size,
                              hipStream_t stream) {
    const float* x      = (const float*)d_in[0];   // (16, 18) float32
    const float* params = (const float*)d_in[1];   // (72,)   float32
    float* out          = (float*)d_out;           // (16, 18) float32

    const int total = NBATCH * NQ;                 // 288 threads
    const int block = 64;
    const int grid  = (total + block - 1) / block; // 5 blocks
    qnn_lightcone_kernel<<<grid, block, 0, stream>>>(x, params, out);
}

// Round 2
// 10.052 us; speedup vs baseline: 1.3931x; 1.3931x over previous
//
#include <hip/hip_runtime.h>
#include <math.h>

// EstimatorQNN: 18-qubit circuit, depth 3, nearest-neighbor CZ.
// Exact light-cone reduction: <Z_i> depends only on qubits [i-2, i+2]
// (final CZ layer is diagonal -> commutes with Z_i; support grows by 1
// qubit per *inner* CZ layer only). Each (batch, qubit) output is an
// independent 5-qubit (32-amplitude) simulation held fully in registers.
//
// R2: replace libm sincosf (full range reduction, ~100 VALU ops, serial)
// with hardware v_sin/v_cos via __sinf/__cosf (~4 ops). 288 threads have
// no TLP to hide serial latency, so this cuts the critical path ~3x.
// Error headroom: absmax was 4.9e-4 vs 1.35e-2 threshold.

#define NQ    18
#define NDEPTH 3
#define NBATCH 16
#define WQ     5      // window qubits
#define WA    32      // window amplitudes (2^WQ)

__global__ __launch_bounds__(64)
void qnn_lightcone_kernel(const float* __restrict__ x,
                          const float* __restrict__ params,
                          float* __restrict__ out) {
    const int tid = blockIdx.x * blockDim.x + threadIdx.x;
    if (tid >= NBATCH * NQ) return;
    const int b = tid / NQ;
    const int i = tid - b * NQ;

    // clamped 5-qubit window [s, s+4], target local position p
    int s = i - 2;
    if (s < 0) s = 0;
    if (s > NQ - WQ) s = NQ - WQ;
    const int p = i - s;

    // --- angles: cos/sin of theta/2 (hardware trig) ---
    float cx[WQ], sx[WQ];
    float cw[NDEPTH][WQ], sw[NDEPTH][WQ];
#pragma unroll
    for (int q = 0; q < WQ; ++q) {
        const float th = 0.5f * x[b * NQ + s + q];
        sx[q] = __sinf(th);
        cx[q] = __cosf(th);
    }
#pragma unroll
    for (int d = 0; d < NDEPTH; ++d) {
#pragma unroll
        for (int q = 0; q < WQ; ++q) {
            const float th = 0.5f * params[NQ + d * NQ + s + q];
            sw[d][q] = __sinf(th);
            cw[d][q] = __cosf(th);
        }
    }

    // --- state: 32 complex amplitudes in registers, |00000> start ---
    float sr[WA], si[WA];
#pragma unroll
    for (int a = 0; a < WA; ++a) { sr[a] = 0.0f; si[a] = 0.0f; }
    sr[0] = 1.0f;

    // --- RX layer: v0' = c*v0 - i s*v1 ; v1' = -i s*v0 + c*v1 ---
#pragma unroll
    for (int q = 0; q < WQ; ++q) {
        const float c = cx[q], sn = sx[q];
#pragma unroll
        for (int a = 0; a < WA; ++a) {
            if (a & (1 << q)) continue;
            const int a1 = a | (1 << q);
            const float r0 = sr[a], i0 = si[a], r1 = sr[a1], i1 = si[a1];
            sr[a]  = c * r0 + sn * i1;
            si[a]  = c * i0 - sn * r1;
            sr[a1] = c * r1 + sn * i0;
            si[a1] = c * i1 - sn * r0;
        }
    }

    // --- depth layers: RY sweep then CZ chain (window-internal) ---
#pragma unroll
    for (int d = 0; d < NDEPTH; ++d) {
#pragma unroll
        for (int q = 0; q < WQ; ++q) {
            const float c = cw[d][q], sn = sw[d][q];
#pragma unroll
            for (int a = 0; a < WA; ++a) {
                if (a & (1 << q)) continue;
                const int a1 = a | (1 << q);
                const float r0 = sr[a], i0 = si[a], r1 = sr[a1], i1 = si[a1];
                sr[a]  = c * r0 - sn * r1;
                si[a]  = c * i0 - sn * i1;
                sr[a1] = sn * r0 + c * r1;
                si[a1] = sn * i0 + c * i1;
            }
        }
#pragma unroll
        for (int q = 0; q < WQ - 1; ++q) {
            const int m = (1 << q) | (1 << (q + 1));
#pragma unroll
            for (int a = 0; a < WA; ++a) {
                if ((a & m) == m) { sr[a] = -sr[a]; si[a] = -si[a]; }
            }
        }
    }

    // --- <Z_p> = sum |amp|^2 * (+1 if bit p == 0 else -1) ---
    float z = 0.0f;
#pragma unroll
    for (int a = 0; a < WA; ++a) {
        const float pr = sr[a] * sr[a] + si[a] * si[a];
        z += ((a >> p) & 1) ? -pr : pr;
    }
    out[b * NQ + i] = z;
}

extern "C" void kernel_launch(void* const* d_in, const int* in_sizes, int n_in,
                              void* d_out, int out_size, void* d_ws, size_t ws_size,
                              hipStream_t stream) {
    const float* x      = (const float*)d_in[0];   // (16, 18) float32
    const float* params = (const float*)d_in[1];   // (72,)   float32
    float* out          = (float*)d_out;           // (16, 18) float32

    const int total = NBATCH * NQ;                 // 288 threads
    const int block = 64;
    const int grid  = (total + block - 1) / block; // 5 blocks
    qnn_lightcone_kernel<<<grid, block, 0, stream>>>(x, params, out);
}